// Round 8
// baseline (72.101 us; speedup 1.0000x reference)
//
#include <hip/hip_runtime.h>

#define CIN 27
#define HH 64
#define WW 64
#define OC 32
#define TW 16            // tile width (pixels)
#define TH 16            // tile height (pixels)
#define RS 20            // LDS row stride (dwords)
#define CS (18 * RS)     // 360 dwords per channel slab
#define WS 12            // padded per-channel weight stride (48B, 16B-aligned)
// LDS: 27*360*4 + 27*12*4 = 40176 B -> 4 blocks/CU. 256-thr blocks, 1 px/thread:
// 16 waves/CU = 4 waves/SIMD (double R6's occupancy — the TLP experiment).

__device__ __forceinline__ float maj3(float a, float b, float c) {
    // Exact closed form of bipolar 3-input majority gate: (a + b + c - a*b*c)/2
    float s = a + b + c;
    return 0.5f * fmaf(-(a * b), c, s);
}

__global__ __launch_bounds__(256, 4) void sconv_maj_kernel(
    const float* __restrict__ x,    // [N, CIN, 64, 64]
    const float* __restrict__ wgt,  // [OC, CIN, 3, 3]
    float* __restrict__ out)        // [N, OC, 64, 64]
{
    __shared__ __align__(16) float sw[CIN * WS];
    __shared__ __align__(16) float sx[CIN * CS];

    const int tx = threadIdx.x;            // 0..15 (pixel col)
    const int ty = threadIdx.y;            // 0..15 (pixel row)
    const int tid = ty * 16 + tx;
    const int tile_w0 = blockIdx.x * TW;
    const int tile_h0 = blockIdx.y * TH;
    const int n  = blockIdx.z >> 5;        // OC = 32
    const int oc = blockIdx.z & 31;

    // ---- stage weights (block-uniform oc) into padded LDS slots ----
    if (tid < CIN * 9) {
        int c = tid / 9;
        int k = tid - 9 * c;
        sw[c * WS + k] = wgt[oc * (CIN * 9) + tid];
    }

    // ---- stage x tile with 1-halo (single pass, all 27 channels) ----
    const float* xn = x + (size_t)n * (CIN * HH * WW);
    for (int pos = tid; pos < 18 * 18; pos += 256) {
        int r   = pos / 18;
        int col = pos - 18 * r;
        int gr = tile_h0 + r - 1;
        int gc = tile_w0 + col - 1;
        bool ok = ((unsigned)gr < (unsigned)HH) & ((unsigned)gc < (unsigned)WW);
        int off = ok ? (gr * WW + gc) : 0;     // clamped addr, select after load
        float* lp = sx + r * RS + col;
        #pragma unroll
        for (int c = 0; c < CIN; ++c) {
            float raw = xn[(size_t)c * (HH * WW) + off];
            lp[c * CS] = ok ? raw : 0.0f;
        }
    }
    __syncthreads();

    // ---- 5-level majority tree, 1 pixel/thread, folded as-you-go ----
    // Per (c,ki): reads sx[base], sx[base+1], sx[base+2] -> compiler merges the
    // stride-2 pair into ds_read2_b32; 2 LDS instrs per row.
    float m4[3];
    #pragma unroll
    for (int q = 0; q < 3; ++q) {              // level-4 group (9 channels)
        float m3[3];
        #pragma unroll
        for (int t = 0; t < 3; ++t) {          // level-3 group (3 channels)
            float m2[3];
            #pragma unroll
            for (int u = 0; u < 3; ++u) {      // channel within triple
                const int c = q * 9 + t * 3 + u;
                float4 wa = *(const float4*)&sw[c * WS];      // w0..w3 broadcast
                float4 wb = *(const float4*)&sw[c * WS + 4];  // w4..w7
                float  w8 = sw[c * WS + 8];
                const float wk[9] = {wa.x, wa.y, wa.z, wa.w,
                                     wb.x, wb.y, wb.z, wb.w, w8};
                float m1[3];
                #pragma unroll
                for (int ki = 0; ki < 3; ++ki) {
                    const float* row = &sx[c * CS + (ty + ki) * RS + tx];
                    float v0 = row[0];
                    float v1 = row[1];
                    float v2 = row[2];
                    float p0 = v0 * wk[ki * 3 + 0];
                    float p1 = v1 * wk[ki * 3 + 1];
                    float p2 = v2 * wk[ki * 3 + 2];
                    m1[ki] = maj3(p0, p1, p2);
                }
                m2[u] = maj3(m1[0], m1[1], m1[2]);
            }
            m3[t] = maj3(m2[0], m2[1], m2[2]);   // fold immediately
        }
        m4[q] = maj3(m3[0], m3[1], m3[2]);       // fold immediately
    }
    float res = maj3(m4[0], m4[1], m4[2]);

    const int h = tile_h0 + ty;
    const int w = tile_w0 + tx;
    out[(((size_t)n * OC + oc) * HH + h) * WW + w] = res;
}

extern "C" void kernel_launch(void* const* d_in, const int* in_sizes, int n_in,
                              void* d_out, int out_size, void* d_ws, size_t ws_size,
                              hipStream_t stream) {
    const float* x   = (const float*)d_in[0];
    const float* wgt = (const float*)d_in[1];
    float* out = (float*)d_out;

    dim3 block(16, 16, 1);                // 256 threads, 4 waves
    dim3 grid(WW / TW, HH / TH, 2 * OC);  // (4,4,64) = 1024 blocks, 4/CU, fully resident
    sconv_maj_kernel<<<grid, block, 0, stream>>>(x, wgt, out);
}

// Round 9
// 70.557 us; speedup vs baseline: 1.0219x; 1.0219x over previous
//
#include <hip/hip_runtime.h>

#define CIN 27
#define CG  9            // channels per block = one level-4 tree group
#define HH 64
#define WW 64
#define OC 32
#define TW 16            // tile width (pixels)
#define TH 16            // tile height (pixels)
#define RS 20            // LDS row stride (dwords), even -> aligned b64 window reads
#define CS (18 * RS)     // 360 dwords per channel slab
#define WS 12            // padded per-channel weight stride
#define NPIX (2 * OC * HH * WW)   // 262144 output pixels (N=2)
// LDS/block: 9*360*4 + 9*12*4 = 12960 + 432 = 13392 B -> 12 blocks/CU (160.7 of 163.8 KB)
// grid z = 192 -> 3072 blocks = 12/CU, 24 waves/CU = 6 waves/SIMD (vs R6's 2).

__device__ __forceinline__ float maj3(float a, float b, float c) {
    // Exact closed form of bipolar 3-input majority gate: (a + b + c - a*b*c)/2
    float s = a + b + c;
    return 0.5f * fmaf(-(a * b), c, s);
}

__device__ __forceinline__ float2 pk_maj3(float2 a, float2 b, float2 c) {
    float2 r;
    r.x = maj3(a.x, b.x, c.x);
    r.y = maj3(a.y, b.y, c.y);
    return r;
}

__global__ __launch_bounds__(128, 6) void sconv_part_kernel(
    const float* __restrict__ x,    // [N, CIN, 64, 64]
    const float* __restrict__ wgt,  // [OC, CIN, 3, 3]
    float* __restrict__ part)       // [3][N*OC*64*64] level-4 partials
{
    __shared__ __align__(16) float sw[CG * WS];
    __shared__ __align__(16) float sx[CG * CS];

    const int tx = threadIdx.x;            // 0..7  (pixel cols 2tx, 2tx+1)
    const int ty = threadIdx.y;            // 0..15
    const int tid = ty * 8 + tx;
    const int tile_w0 = blockIdx.x * TW;
    const int tile_h0 = blockIdx.y * TH;
    const int noc = blockIdx.z & 63;       // same-x blocks adjacent in z for L2 locality
    const int q   = blockIdx.z >> 6;       // tree group 0..2
    const int n  = noc >> 5;
    const int oc = noc & 31;
    const int cbase = q * CG;              // first channel of this group

    // ---- stage this group's 81 weights (block-uniform oc) ----
    if (tid < CG * 9) {
        int c = tid / 9;
        int k = tid - 9 * c;
        sw[c * WS + k] = wgt[oc * (CIN * 9) + (cbase + c) * 9 + k];
    }

    // ---- stage 9-channel x tile with 1-halo ----
    const float* xn = x + (size_t)n * (CIN * HH * WW);
    for (int pos = tid; pos < 18 * 18; pos += 128) {
        int r   = pos / 18;
        int col = pos - 18 * r;
        int gr = tile_h0 + r - 1;
        int gc = tile_w0 + col - 1;
        bool ok = ((unsigned)gr < (unsigned)HH) & ((unsigned)gc < (unsigned)WW);
        int off = ok ? (gr * WW + gc) : 0;
        float* lp = sx + r * RS + col;
        #pragma unroll
        for (int c = 0; c < CG; ++c) {
            float raw = xn[(size_t)(cbase + c) * (HH * WW) + off];
            lp[c * CS] = ok ? raw : 0.0f;
        }
    }
    __syncthreads();

    // ---- levels 1-4 of the majority tree for this 9-channel group ----
    float2 m3[3];
    #pragma unroll
    for (int t = 0; t < 3; ++t) {          // level-3 group (3 channels)
        float2 m2[3];
        #pragma unroll
        for (int u = 0; u < 3; ++u) {      // channel within triple
            const int c = t * 3 + u;       // local channel index
            float4 wa = *(const float4*)&sw[c * WS];      // w0..w3 (broadcast)
            float4 wb = *(const float4*)&sw[c * WS + 4];  // w4..w7
            float  w8 = sw[c * WS + 8];
            const float wk[9] = {wa.x, wa.y, wa.z, wa.w,
                                 wb.x, wb.y, wb.z, wb.w, w8};
            float2 m1[3];
            #pragma unroll
            for (int ki = 0; ki < 3; ++ki) {
                // base dword even -> two aligned ds_read_b64
                const float2* prow =
                    (const float2*)&sx[c * CS + (ty + ki) * RS + 2 * tx];
                float2 v01 = prow[0];   // cols 2tx, 2tx+1
                float2 v23 = prow[1];   // cols 2tx+2, 2tx+3
                float w0 = wk[ki * 3 + 0];
                float w1 = wk[ki * 3 + 1];
                float w2 = wk[ki * 3 + 2];
                // pixel A (col 2tx): v01.x v01.y v23.x ; pixel B: v01.y v23.x v23.y
                float2 p0 = make_float2(v01.x * w0, v01.y * w0);
                float2 p1 = make_float2(v01.y * w1, v23.x * w1);
                float2 p2 = make_float2(v23.x * w2, v23.y * w2);
                m1[ki] = pk_maj3(p0, p1, p2);
            }
            m2[u] = pk_maj3(m1[0], m1[1], m1[2]);
        }
        m3[t] = pk_maj3(m2[0], m2[1], m2[2]);
    }
    float2 m4 = pk_maj3(m3[0], m3[1], m3[2]);   // this block's level-4 value

    const int h = tile_h0 + ty;
    const int w = tile_w0 + 2 * tx;
    float2* po = (float2*)(part + (size_t)q * NPIX + ((size_t)noc * HH + h) * WW + w);
    *po = m4;
}

__global__ __launch_bounds__(256) void sconv_combine_kernel(
    const float* __restrict__ part,  // [3][NPIX]
    float* __restrict__ out)         // [NPIX]
{
    const int i = blockIdx.x * 256 + threadIdx.x;   // float4 index, NPIX/4 total
    const float4* p0 = (const float4*)part;
    const float4* p1 = (const float4*)(part + NPIX);
    const float4* p2 = (const float4*)(part + 2 * (size_t)NPIX);
    float4 a = p0[i], b = p1[i], c = p2[i];
    float4 r;
    r.x = maj3(a.x, b.x, c.x);
    r.y = maj3(a.y, b.y, c.y);
    r.z = maj3(a.z, b.z, c.z);
    r.w = maj3(a.w, b.w, c.w);
    ((float4*)out)[i] = r;
}

extern "C" void kernel_launch(void* const* d_in, const int* in_sizes, int n_in,
                              void* d_out, int out_size, void* d_ws, size_t ws_size,
                              hipStream_t stream) {
    const float* x   = (const float*)d_in[0];
    const float* wgt = (const float*)d_in[1];
    float* out  = (float*)d_out;
    float* part = (float*)d_ws;              // 3 * NPIX * 4 = 3 MB scratch

    dim3 block(8, 16, 1);                    // 128 threads, 2 waves
    dim3 grid(WW / TW, HH / TH, 3 * 2 * OC); // (4,4,192) = 3072 blocks, 12/CU
    sconv_part_kernel<<<grid, block, 0, stream>>>(x, wgt, part);

    // same-stream ordering guarantees part is visible to the combine kernel
    sconv_combine_kernel<<<NPIX / 4 / 256, 256, 0, stream>>>(part, out);
}